// Round 10
// baseline (339.665 us; speedup 1.0000x reference)
//
#include <hip/hip_runtime.h>
#include <math.h>

#define NTOT 262144   // total nodes
#define BG   64       // graphs
#define NNPG 4096     // nodes per graph
#define ET   1048576  // directed edges
#define EPG  16384    // edges per graph
#define HD   128
#define LD   64
#define NSEG 129
#define SLOTPG 28672  // max padded slots per graph (EPG + 3*NNPG)
#define SLOTCAP (BG*SLOTPG)
#define TN   256      // nodes per agg tile (one per thread in phase 1)

// XCD-bijective swizzle for 256 blocks = 64 graphs x 4 sub-blocks:
// b = (g&7) + 8*((g>>3)*4 + j)  ->  all 4 sub-blocks of graph g share b&7 (XCD)
__device__ __forceinline__ void swz(int b, int& g, int& j){
  int xcd = b & 7, q = b >> 3;
  g = (q >> 2)*8 + xcd;
  j = q & 3;
}

// ---- count: per-edge global atomics (XCD-local) + zero acc ----
__global__ void __launch_bounds__(1024) k_count(const int* __restrict__ ei,
                                                int* __restrict__ cnt,
                                                float2* __restrict__ acc){
  int g, j; swz(blockIdx.x, g, j);
  int tid = threadIdx.x;
  acc[blockIdx.x*1024 + tid] = make_float2(0.f, 0.f);   // 256*1024 == NTOT
  const int4* dsts4 = (const int4*)(ei + ET + g*EPG + j*4096);
  int4 D = dsts4[tid];
  atomicAdd(&cnt[D.x], 1); atomicAdd(&cnt[D.y], 1);
  atomicAdd(&cnt[D.z], 1); atomicAdd(&cnt[D.w], 1);
}

// ---- scan: padded per-graph prefix sum, off/cursor/xd, pad fill ----
__global__ void __launch_bounds__(1024) k_scan(const int* __restrict__ cnt,
                                               const float* __restrict__ x,
                                               int* __restrict__ off, int* __restrict__ cursor,
                                               int* __restrict__ csrc, float2* __restrict__ xd){
  __shared__ int tsums[16];
  int g = blockIdx.x, tid = threadIdx.x, gbase = g*NNPG;
  int4 n4 = *(const int4*)(cnt + gbase + 4*tid);
  float4 xv = *(const float4*)(x + gbase + 4*tid);
  int p0 = (n4.x+3)&~3, p1 = (n4.y+3)&~3, p2 = (n4.z+3)&~3, p3 = (n4.w+3)&~3;
  int tsum = p0+p1+p2+p3;
  int lane = tid & 63, wv = tid >> 6;
  int incl = tsum;
  #pragma unroll
  for (int dd = 1; dd < 64; dd <<= 1){
    int v = __shfl_up(incl, dd, 64);
    if (lane >= dd) incl += v;
  }
  if (lane == 63) tsums[wv] = incl;
  __syncthreads();
  if (tid < 64){
    int v = (tid < 16) ? tsums[tid] : 0;
    int inc2 = v;
    #pragma unroll
    for (int dd = 1; dd < 16; dd <<= 1){
      int t2 = __shfl_up(inc2, dd, 64);
      if (tid >= dd) inc2 += t2;
    }
    if (tid < 16) tsums[tid] = inc2 - v;
  }
  __syncthreads();
  int tbase = tsums[wv] + incl - tsum;
  int o0 = g*SLOTPG + tbase, o1 = o0+p0, o2 = o1+p1, o3 = o2+p2;
  int i0 = gbase + 4*tid;
  *(int4*)(off + i0)    = make_int4(o0, o1, o2, o3);
  *(int4*)(cursor + i0) = make_int4(o0, o1, o2, o3);
  float d0 = rsqrtf((float)n4.x + 1.0f), d1 = rsqrtf((float)n4.y + 1.0f);
  float d2 = rsqrtf((float)n4.z + 1.0f), d3 = rsqrtf((float)n4.w + 1.0f);
  float4* xd4 = (float4*)xd;
  xd4[i0/2 + 0] = make_float4(xv.x, d0, xv.y, d1);
  xd4[i0/2 + 1] = make_float4(xv.z, d2, xv.w, d3);
  for (int s = n4.x; s < p0; s++) csrc[o0+s] = -1;
  for (int s = n4.y; s < p1; s++) csrc[o1+s] = -1;
  for (int s = n4.z; s < p2; s++) csrc[o2+s] = -1;
  for (int s = n4.w; s < p3; s++) csrc[o3+s] = -1;
}

// ---- place + ax/s1 accumulate (global, XCD-local); block 256 runs tab1 ----
// tab1: relu(a*w1[j]+b1[j]) piecewise-linear; incremental over rank-sorted flips.
// AC float layout: s*256 + (k>>2)*8 + (k&3), +4 for C
__global__ void __launch_bounds__(1024) k_place(
    const int* __restrict__ ei, const float2* __restrict__ xd,
    int* __restrict__ cursor, int* __restrict__ csrc, float2* __restrict__ acc,
    const float* __restrict__ w1, const float* __restrict__ b1,
    const float* __restrict__ w2,
    float* __restrict__ t1, float* __restrict__ AC1, int* __restrict__ nfp)
{
  __shared__ float w2s[HD*HD];
  __shared__ float tss[128], wss[128], bss[128];
  __shared__ int kss[128], jrs[128];
  int tid = threadIdx.x;
  if (blockIdx.x == 256){
    {
      const float4* src = (const float4*)w2;
      float4* dst = (float4*)w2s;
      for (int idx = tid; idx < HD*HD/4; idx += 1024) dst[idx] = src[idx];
    }
    if (tid < 128){
      float w = w1[tid], b = b1[tid];
      float t; int kind;
      if (w != 0.0f){ t = -b / w; kind = (w > 0.0f) ? 0 : 1; }
      else          { t = INFINITY; kind = 2; }
      tss[tid] = t; kss[tid] = kind; wss[tid] = w; bss[tid] = b;
      jrs[tid] = -1;
    }
    __syncthreads();
    if (tid == 0){
      int c = 0;
      for (int q = 0; q < 128; q++) c += (kss[q] != 2) ? 1 : 0;
      nfp[0] = c;
    }
    if (tid < 128){
      int j = tid;
      float t = tss[j];
      int r = 0;
      for (int q = 0; q < 128; q++){
        if (kss[q] != 2){
          float tq = tss[q];
          if (tq < t || (tq == t && q < j)) r++;
        }
      }
      t1[j] = t;
      if (kss[j] != 2) jrs[r] = j;
    }
    __syncthreads();
    if (tid < 128){
      int k = tid;
      float a = 0.f, c = 0.f;
      for (int q = 0; q < 128; q++){    // segment 0: kind1 all active
        int kd = kss[q];
        bool act = (kd == 1) || (kd == 2 && bss[q] > 0.0f);
        if (act){ float v = w2s[q*HD + k]; a = fmaf(wss[q], v, a); c = fmaf(bss[q], v, c); }
      }
      int base = (k>>2)*8 + (k&3);
      AC1[base] = a; AC1[base+4] = c;
      for (int s = 0; s < 128; s++){
        int q = jrs[s];
        if (q >= 0){
          float sg = (kss[q] == 0) ? 1.f : -1.f;
          float v  = w2s[q*HD + k];
          a = fmaf(sg*wss[q], v, a);
          c = fmaf(sg*bss[q], v, c);
        }
        int o = (s+1)*256 + base;
        AC1[o] = a; AC1[o+4] = c;
      }
    }
    return;
  }
  int g, j; swz(blockIdx.x, g, j);
  const int4* srcs4 = (const int4*)(ei + g*EPG + j*4096);
  const int4* dsts4 = (const int4*)(ei + ET + g*EPG + j*4096);
  int4 S = srcs4[tid], D = dsts4[tid];
  float* accf = (float*)acc;
  #define PLACE1(s_, d_) { \
    float2 sd_ = xd[s_]; \
    int p_ = atomicAdd(&cursor[d_], 1); \
    csrc[p_] = (s_); \
    atomicAdd(&accf[2*(d_)],   sd_.y * sd_.x); \
    atomicAdd(&accf[2*(d_)+1], sd_.y); }
  PLACE1(S.x, D.x); PLACE1(S.y, D.y); PLACE1(S.z, D.z); PLACE1(S.w, D.w);
  #undef PLACE1
}

// ---- pack per-node records (gather-free): recN[2i]=(d, d*ax, d*srow, segE),
// recN[2i+1]=(eo,np,0,0); srowA for decoder segs
__global__ void k_pack(const float2* __restrict__ xd, const float2* __restrict__ acc,
                       const int* __restrict__ off, const int* __restrict__ cnt,
                       const float* __restrict__ t1,
                       float4* __restrict__ recN, float* __restrict__ srowA){
  __shared__ float ts[128];
  if (threadIdx.x < 128) ts[threadIdx.x] = t1[threadIdx.x];
  __syncthreads();
  int i = blockIdx.x*256 + threadIdx.x;
  int n = cnt[i], eo = off[i];
  float di = rsqrtf((float)n + 1.0f);
  float2 xdv = xd[i];
  float2 a2 = acc[i];
  float ax = di * (di * xdv.x + a2.x);
  float sr = di * (di + a2.y);
  int sc = 0;
  for (int q = 0; q < 128; q++) sc += (ts[q] < ax) ? 1 : 0;
  int np = (n + 3) & ~3;
  recN[2*i]   = make_float4(di, di*ax, di*sr, __int_as_float(sc));
  recN[2*i+1] = make_float4(__int_as_float(eo), __int_as_float(np), 0.f, 0.f);
  srowA[i] = sr;
}

// ---------------- fused encoder GCN2 + relu + mean-pool ----------------
__global__ void __launch_bounds__(256) k_enc_agg(
    const float4* __restrict__ recN, const int* __restrict__ csrc,
    const float4* __restrict__ AC, const float* __restrict__ b2,
    const int* __restrict__ nfp, float* __restrict__ hgsum)
{
  __shared__ float4 sS[TN];
  __shared__ float4 sRA[TN];
  __shared__ int sFlag[TN];
  __shared__ float red[256*4];
  int bid = blockIdx.x, g = bid & 63, part = bid >> 6;   // 1024 blocks
  int tid = threadIdx.x, lane = tid & 31, nrow = tid >> 5;
  int base = g*NNPG + part*TN;
  int nf = nfp[0];
  {
    int i = base + tid;
    sRA[tid] = recN[2*i];
    float4 rB = recN[2*i+1];
    int eo = __float_as_int(rB.x), np = __float_as_int(rB.y);
    float swa=0.f, sw=0.f, swaN=0.f, swN=0.f;
    int flag = 0;
    for (int t = 0; t < np; t += 4){
      int4 ss = *(const int4*)(csrc + eo + t);
      #pragma unroll
      for (int uu = 0; uu < 4; uu++){
        int s = (uu==0)?ss.x:(uu==1)?ss.y:(uu==2)?ss.z:ss.w;
        if (s >= 0){
          float4 r = recN[2*s];
          int sb = __float_as_int(r.w);
          swa += r.y; sw += r.x;
          bool isN = (sb == nf) && (sb != 0);
          swaN += isN ? r.y : 0.f;
          swN  += isN ? r.x : 0.f;
          flag |= (sb != 0 && sb != nf) ? 1 : 0;
        }
      }
    }
    sS[tid] = make_float4(swa, sw, swaN, swN);
    sFlag[tid] = flag;
  }
  __syncthreads();
  const float4* q0 = AC + (size_t)lane*2;
  const float4* qn = AC + ((size_t)nf*32 + lane)*2;
  float4 A0 = q0[0], C0 = q0[1], An = qn[0], Cn = qn[1];
  float4 dA = make_float4(An.x-A0.x, An.y-A0.y, An.z-A0.z, An.w-A0.w);
  float4 dC = make_float4(Cn.x-C0.x, Cn.y-C0.y, Cn.z-C0.z, Cn.w-C0.w);
  float4 bb = ((const float4*)b2)[lane];
  float gx=0.f, gy=0.f, gz=0.f, gw=0.f;
  for (int it = 0; it < TN/8; ++it){
    int li = it*8 + nrow;
    int i = base + li;
    float4 rA = sRA[li];
    float accx, accy, accz, accw;
    if (sFlag[li]){              // rare slow path: full 32-wide recompute
      float4 rB = recN[2*i+1];
      int eo = __float_as_int(rB.x), np = __float_as_int(rB.y);
      float swa=0.f, sw=0.f, swaN=0.f, swN=0.f;
      float mx=0.f, my=0.f, mz=0.f, mw=0.f;
      for (int t = 0; t < np; ++t){
        int s = csrc[eo+t];
        if (s < 0) continue;
        float4 r = recN[2*s];
        int sb = __float_as_int(r.w);
        float v = r.y;
        swa += v; sw += r.x;
        bool isN = (sb == nf) && (sb != 0);
        swaN += isN ? v : 0.f; swN += isN ? r.x : 0.f;
        if (sb != 0 && sb != nf){
          const float4* qm = AC + ((size_t)sb*32 + lane)*2;
          float4 qa = qm[0], qc = qm[1];
          mx = fmaf(v, qa.x-A0.x, fmaf(r.x, qc.x-C0.x, mx));
          my = fmaf(v, qa.y-A0.y, fmaf(r.x, qc.y-C0.y, my));
          mz = fmaf(v, qa.z-A0.z, fmaf(r.x, qc.z-C0.z, mz));
          mw = fmaf(v, qa.w-A0.w, fmaf(r.x, qc.w-C0.w, mw));
        }
      }
      accx = fmaf(swa,A0.x, fmaf(swaN,dA.x, fmaf(sw,C0.x, fmaf(swN,dC.x, mx))));
      accy = fmaf(swa,A0.y, fmaf(swaN,dA.y, fmaf(sw,C0.y, fmaf(swN,dC.y, my))));
      accz = fmaf(swa,A0.z, fmaf(swaN,dA.z, fmaf(sw,C0.z, fmaf(swN,dC.z, mz))));
      accw = fmaf(swa,A0.w, fmaf(swaN,dA.w, fmaf(sw,C0.w, fmaf(swN,dC.w, mw))));
    } else {
      float4 s4 = sS[li];
      accx = fmaf(s4.x,A0.x, fmaf(s4.z,dA.x, fmaf(s4.y,C0.x, s4.w*dC.x)));
      accy = fmaf(s4.x,A0.y, fmaf(s4.z,dA.y, fmaf(s4.y,C0.y, s4.w*dC.y)));
      accz = fmaf(s4.x,A0.z, fmaf(s4.z,dA.z, fmaf(s4.y,C0.z, s4.w*dC.z)));
      accw = fmaf(s4.x,A0.w, fmaf(s4.z,dA.w, fmaf(s4.y,C0.w, s4.w*dC.w)));
    }
    int si = __float_as_int(rA.w);
    bool m0 = (si == 0);
    float4 sa, sc;
    sa.x = m0 ? A0.x : An.x; sa.y = m0 ? A0.y : An.y; sa.z = m0 ? A0.z : An.z; sa.w = m0 ? A0.w : An.w;
    sc.x = m0 ? C0.x : Cn.x; sc.y = m0 ? C0.y : Cn.y; sc.z = m0 ? C0.z : Cn.z; sc.w = m0 ? C0.w : Cn.w;
    if (si != 0 && si != nf){
      const float4* qs = AC + ((size_t)si*32 + lane)*2;
      sa = qs[0]; sc = qs[1];
    }
    float d = rA.x, d2 = d*d, ca = rA.y*d;
    gx += fmaxf(fmaf(d, accx, fmaf(ca, sa.x, d2*sc.x)) + bb.x, 0.f);
    gy += fmaxf(fmaf(d, accy, fmaf(ca, sa.y, d2*sc.y)) + bb.y, 0.f);
    gz += fmaxf(fmaf(d, accz, fmaf(ca, sa.z, d2*sc.z)) + bb.z, 0.f);
    gw += fmaxf(fmaf(d, accw, fmaf(ca, sa.w, d2*sc.w)) + bb.w, 0.f);
  }
  __syncthreads();
  red[tid*4+0] = gx; red[tid*4+1] = gy; red[tid*4+2] = gz; red[tid*4+3] = gw;
  __syncthreads();
  if (nrow == 0){
    float tx=0.f, ty=0.f, tz=0.f, tw=0.f;
    for (int r2 = 0; r2 < 8; r2++){
      int t2 = (r2*32 + lane)*4;
      tx += red[t2]; ty += red[t2+1]; tz += red[t2+2]; tw += red[t2+3];
    }
    atomicAdd(&hgsum[g*HD + lane*4 + 0], tx);
    atomicAdd(&hgsum[g*HD + lane*4 + 1], ty);
    atomicAdd(&hgsum[g*HD + lane*4 + 2], tz);
    atomicAdd(&hgsum[g*HD + lane*4 + 3], tw);
  }
}

// ------- per-graph dense chain (slim: no table build) -------
__global__ void __launch_bounds__(128) k_small(
    const float* __restrict__ hgsum,
    const float* __restrict__ mu_w, const float* __restrict__ mu_b,
    const float* __restrict__ lv_w, const float* __restrict__ lv_b,
    const float* __restrict__ eps,
    const float* __restrict__ zn_w, const float* __restrict__ zn_b,
    const float* __restrict__ dec_w1, const float* __restrict__ dec_b1,
    float* __restrict__ out_mu, float* __restrict__ out_lv, float* __restrict__ out_z,
    float* __restrict__ t2, float* __restrict__ ushG, int* __restrict__ nf2)
{
  int g = blockIdx.x, tid = threadIdx.x;
  __shared__ float hg[128], zsh[64], znsh[128];
  __shared__ int ks[128];
  hg[tid] = hgsum[g*HD + tid] * (1.0f/4096.0f);
  __syncthreads();
  if (tid < 64){
    int l = tid;
    float m = mu_b[l], v = lv_b[l];
    for (int k = 0; k < HD; k++){
      float hv = hg[k];
      m = fmaf(hv, mu_w[k*LD + l], m);
      v = fmaf(hv, lv_w[k*LD + l], v);
    }
    int o = g*LD + l;
    out_mu[o] = m; out_lv[o] = v;
    float zv = fmaf(expf(0.5f*v), eps[o], m);
    out_z[o] = zv; zsh[l] = zv;
  }
  __syncthreads();
  {
    int k = tid;
    float acc = zn_b[k];
    for (int l = 0; l < LD; l++) acc = fmaf(zsh[l], zn_w[l*HD + k], acc);
    znsh[k] = acc;
  }
  __syncthreads();
  float w;
  {
    int k = tid;
    float acc = 0.f;
    for (int j = 0; j < HD; j++) acc = fmaf(znsh[j], dec_w1[j*HD + k], acc);
    ushG[g*HD + k] = acc;
    w = acc;
  }
  float b = dec_b1[tid];
  float t; int kind;
  if (w != 0.0f){ t = -b / w; kind = (w > 0.0f) ? 0 : 1; }
  else          { t = INFINITY; kind = 2; }
  t2[g*HD + tid] = t; ks[tid] = kind;
  __syncthreads();
  if (tid == 0){
    int c = 0;
    for (int q = 0; q < 128; q++) c += (ks[q] != 2) ? 1 : 0;
    nf2[g] = c;
  }
}

// segD per node -> overwrite recN[2i].y (d*ax, dead after encoder) + used bitmap
__global__ void k_seg2(const float* __restrict__ t2, const float* __restrict__ srowA,
                       float* __restrict__ recNf, int* __restrict__ segUsed){
  __shared__ float ts[128];
  __shared__ int used[8];
  int tid = threadIdx.x;
  int i = blockIdx.x*256 + tid;
  int g = blockIdx.x >> 4;
  if (tid < 128) ts[tid] = t2[g*HD + tid];
  if (tid < 8) used[tid] = 0;
  __syncthreads();
  float a = srowA[i];
  int sc = 0;
  for (int q = 0; q < 128; q++) sc += (ts[q] < a) ? 1 : 0;
  recNf[(2*i)*4 + 1] = __int_as_float(sc);
  atomicOr(&used[sc>>5], 1u << (sc & 31));
  __syncthreads();
  if (tid < 8 && used[tid]) atomicOr(&segUsed[g*8 + tid], used[tid]);
}

// ---- build only the USED decoder table rows (plus rows 0 and nf) ----
__global__ void __launch_bounds__(128) k_tab2rows(
    const float* __restrict__ ushG, const float* __restrict__ dec_b1,
    const float* __restrict__ w2, const int* __restrict__ segUsed,
    const int* __restrict__ nf2, float* __restrict__ AC2)
{
  __shared__ float w2s[HD*HD];
  __shared__ float ws[128], bs[128], tsh[128];
  __shared__ int ks[128], rr[128];
  int g = blockIdx.x, j = threadIdx.x;
  {
    const float4* src = (const float4*)w2;
    float4* dst = (float4*)w2s;
    #pragma unroll
    for (int idx = 0; idx < HD*HD/4/128; idx++) dst[idx*128 + j] = src[idx*128 + j];
  }
  float w = ushG[g*HD + j], b = dec_b1[j];
  float t; int kind;
  if (w != 0.0f){ t = -b / w; kind = (w > 0.0f) ? 0 : 1; }
  else          { t = INFINITY; kind = 2; }
  ws[j] = w; bs[j] = b; tsh[j] = t; ks[j] = kind;
  __syncthreads();
  int r = 0;
  for (int q = 0; q < 128; q++){
    if (ks[q] != 2){
      float tq = tsh[q];
      if (tq < t || (tq == t && q < j)) r++;
    }
  }
  rr[j] = r;
  __syncthreads();
  int nf = nf2[g];
  float* ACg = AC2 + (size_t)g*NSEG*256;
  int base = (j>>2)*8 + (j&3);
  for (int wd = 0; wd < 5; wd++){
    unsigned m = (unsigned)segUsed[g*8 + wd];
    if (wd == 0) m |= 1u;
    if ((nf >> 5) == wd) m |= 1u << (nf & 31);
    while (m){
      int bit = __ffs(m) - 1;
      m &= m - 1;
      int s = wd*32 + bit;
      float a = 0.f, c = 0.f;
      #pragma unroll 8
      for (int q = 0; q < 128; q++){
        int kd = ks[q];
        bool act = (kd == 0) ? (rr[q] < s) : (kd == 1) ? (rr[q] >= s) : (bs[q] > 0.0f);
        float v = act ? w2s[q*HD + j] : 0.0f;
        a = fmaf(ws[q], v, a); c = fmaf(bs[q], v, c);
      }
      ACg[s*256 + base] = a; ACg[s*256 + base + 4] = c;
    }
  }
}

// ---------------- fused decoder GCN2 + relu + out-proj + tanh ----------------
// recN[2i] = (d, segD, d*srow, segE_unused)
__global__ void __launch_bounds__(256) k_dec_agg(
    const float4* __restrict__ recN, const int* __restrict__ csrc,
    const float4* __restrict__ AC2, const float* __restrict__ b2,
    const float* __restrict__ ow, const float* __restrict__ ob,
    const int* __restrict__ nf2, float* __restrict__ recon)
{
  __shared__ float4 sS[TN];
  __shared__ float4 sRA[TN];
  __shared__ int sFlag[TN];
  int bid = blockIdx.x, g = bid & 63, part = bid >> 6;
  int tid = threadIdx.x, lane = tid & 31, nrow = tid >> 5;
  int base = g*NNPG + part*TN;
  int nf = nf2[g];
  const float4* AC = AC2 + (size_t)g*NSEG*64;
  {
    int i = base + tid;
    sRA[tid] = recN[2*i];
    float4 rB = recN[2*i+1];
    int eo = __float_as_int(rB.x), np = __float_as_int(rB.y);
    float swa=0.f, sw=0.f, swaN=0.f, swN=0.f;
    int flag = 0;
    for (int t = 0; t < np; t += 4){
      int4 ss = *(const int4*)(csrc + eo + t);
      #pragma unroll
      for (int uu = 0; uu < 4; uu++){
        int s = (uu==0)?ss.x:(uu==1)?ss.y:(uu==2)?ss.z:ss.w;
        if (s >= 0){
          float4 r = recN[2*s];
          int sb = __float_as_int(r.y);
          swa += r.z; sw += r.x;
          bool isN = (sb == nf) && (sb != 0);
          swaN += isN ? r.z : 0.f;
          swN  += isN ? r.x : 0.f;
          flag |= (sb != 0 && sb != nf) ? 1 : 0;
        }
      }
    }
    sS[tid] = make_float4(swa, sw, swaN, swN);
    sFlag[tid] = flag;
  }
  __syncthreads();
  const float4* q0 = AC + (size_t)lane*2;
  const float4* qn = AC + ((size_t)nf*32 + lane)*2;
  float4 A0 = q0[0], C0 = q0[1], An = qn[0], Cn = qn[1];
  float4 dA = make_float4(An.x-A0.x, An.y-A0.y, An.z-A0.z, An.w-A0.w);
  float4 dC = make_float4(Cn.x-C0.x, Cn.y-C0.y, Cn.z-C0.z, Cn.w-C0.w);
  float4 bb  = ((const float4*)b2)[lane];
  float4 owv = ((const float4*)ow)[lane];
  float obv = ob[0];
  for (int it = 0; it < TN/8; ++it){
    int li = it*8 + nrow;
    int i = base + li;
    float4 rA = sRA[li];
    float accx, accy, accz, accw;
    if (sFlag[li]){              // rare slow path
      float4 rB = recN[2*i+1];
      int eo = __float_as_int(rB.x), np = __float_as_int(rB.y);
      float swa=0.f, sw=0.f, swaN=0.f, swN=0.f;
      float mx=0.f, my=0.f, mz=0.f, mw=0.f;
      for (int t = 0; t < np; ++t){
        int s = csrc[eo+t];
        if (s < 0) continue;
        float4 r = recN[2*s];
        int sb = __float_as_int(r.y);
        float v = r.z;
        swa += v; sw += r.x;
        bool isN = (sb == nf) && (sb != 0);
        swaN += isN ? v : 0.f; swN += isN ? r.x : 0.f;
        if (sb != 0 && sb != nf){
          const float4* qm = AC + ((size_t)sb*32 + lane)*2;
          float4 qa = qm[0], qc = qm[1];
          mx = fmaf(v, qa.x-A0.x, fmaf(r.x, qc.x-C0.x, mx));
          my = fmaf(v, qa.y-A0.y, fmaf(r.x, qc.y-C0.y, my));
          mz = fmaf(v, qa.z-A0.z, fmaf(r.x, qc.z-C0.z, mz));
          mw = fmaf(v, qa.w-A0.w, fmaf(r.x, qc.w-C0.w, mw));
        }
      }
      accx = fmaf(swa,A0.x, fmaf(swaN,dA.x, fmaf(sw,C0.x, fmaf(swN,dC.x, mx))));
      accy = fmaf(swa,A0.y, fmaf(swaN,dA.y, fmaf(sw,C0.y, fmaf(swN,dC.y, my))));
      accz = fmaf(swa,A0.z, fmaf(swaN,dA.z, fmaf(sw,C0.z, fmaf(swN,dC.z, mz))));
      accw = fmaf(swa,A0.w, fmaf(swaN,dA.w, fmaf(sw,C0.w, fmaf(swN,dC.w, mw))));
    } else {
      float4 s4 = sS[li];
      accx = fmaf(s4.x,A0.x, fmaf(s4.z,dA.x, fmaf(s4.y,C0.x, s4.w*dC.x)));
      accy = fmaf(s4.x,A0.y, fmaf(s4.z,dA.y, fmaf(s4.y,C0.y, s4.w*dC.y)));
      accz = fmaf(s4.x,A0.z, fmaf(s4.z,dA.z, fmaf(s4.y,C0.z, s4.w*dC.z)));
      accw = fmaf(s4.x,A0.w, fmaf(s4.z,dA.w, fmaf(s4.y,C0.w, s4.w*dC.w)));
    }
    int si = __float_as_int(rA.y);
    bool m0 = (si == 0);
    float4 sa, sc;
    sa.x = m0 ? A0.x : An.x; sa.y = m0 ? A0.y : An.y; sa.z = m0 ? A0.z : An.z; sa.w = m0 ? A0.w : An.w;
    sc.x = m0 ? C0.x : Cn.x; sc.y = m0 ? C0.y : Cn.y; sc.z = m0 ? C0.z : Cn.z; sc.w = m0 ? C0.w : Cn.w;
    if (si != 0 && si != nf){
      const float4* qs = AC + ((size_t)si*32 + lane)*2;
      sa = qs[0]; sc = qs[1];
    }
    float d = rA.x, d2 = d*d, ca = rA.z*d;
    float hx = fmaxf(fmaf(d, accx, fmaf(ca, sa.x, d2*sc.x)) + bb.x, 0.f);
    float hy = fmaxf(fmaf(d, accy, fmaf(ca, sa.y, d2*sc.y)) + bb.y, 0.f);
    float hz = fmaxf(fmaf(d, accz, fmaf(ca, sa.z, d2*sc.z)) + bb.z, 0.f);
    float hw = fmaxf(fmaf(d, accw, fmaf(ca, sa.w, d2*sc.w)) + bb.w, 0.f);
    float dsum = hx*owv.x + hy*owv.y + hz*owv.z + hw*owv.w;
    for (int o2 = 16; o2 > 0; o2 >>= 1) dsum += __shfl_down(dsum, o2, 32);
    if (lane == 0) recon[i] = tanhf(dsum + obv);
  }
}

// ---------------- launch ----------------
extern "C" void kernel_launch(void* const* d_in, const int* in_sizes, int n_in,
                              void* d_out, int out_size, void* d_ws, size_t ws_size,
                              hipStream_t stream){
  (void)in_sizes; (void)n_in; (void)out_size; (void)ws_size;
  const float* x      = (const float*)d_in[0];
  const float* eps    = (const float*)d_in[1];
  const float* enc_w1 = (const float*)d_in[2];
  const float* enc_b1 = (const float*)d_in[3];
  const float* enc_w2 = (const float*)d_in[4];
  const float* enc_b2 = (const float*)d_in[5];
  const float* mu_w   = (const float*)d_in[6];
  const float* mu_b   = (const float*)d_in[7];
  const float* lv_w   = (const float*)d_in[8];
  const float* lv_b   = (const float*)d_in[9];
  const float* zn_w   = (const float*)d_in[10];
  const float* zn_b   = (const float*)d_in[11];
  const float* dec_w1 = (const float*)d_in[12];
  const float* dec_b1 = (const float*)d_in[13];
  const float* dec_w2 = (const float*)d_in[14];
  const float* dec_b2 = (const float*)d_in[15];
  const float* out_w  = (const float*)d_in[16];
  const float* out_b  = (const float*)d_in[17];
  const int*   ei     = (const int*)d_in[18];

  float* out       = (float*)d_out;
  float* out_recon = out;
  float* out_mu    = out + NTOT;
  float* out_lv    = out_mu + BG*LD;
  float* out_z     = out_lv + BG*LD;

  char* w = (char*)d_ws;
  size_t off_b = 0;
  auto alloc = [&](size_t bytes)->void*{
    void* p = w + off_b;
    off_b += (bytes + 255) & ~(size_t)255;
    return p;
  };
  int*    cnt    = (int*)   alloc((size_t)NTOT*4);
  int*    eoP    = (int*)   alloc((size_t)NTOT*4);
  int*    cursor = (int*)   alloc((size_t)NTOT*4);
  int*    csrc   = (int*)   alloc((size_t)SLOTCAP*4);
  float2* xd     = (float2*)alloc((size_t)NTOT*8);
  float2* acc    = (float2*)alloc((size_t)NTOT*8);
  float4* recN   = (float4*)alloc(((size_t)NTOT*2 + 32)*16);
  float*  srowA  = (float*) alloc((size_t)NTOT*4);
  float*  t1     = (float*) alloc(128*4);
  int*    nf1    = (int*)   alloc(256);
  int*    nf2    = (int*)   alloc(BG*4);
  int*    segU   = (int*)   alloc(BG*8*4);
  float*  ushG   = (float*) alloc((size_t)BG*HD*4);
  float*  AC1    = (float*) alloc((size_t)NSEG*256*4);
  float*  hgsum  = (float*) alloc((size_t)BG*HD*4);
  float*  t2     = (float*) alloc((size_t)BG*HD*4);
  float*  AC2    = (float*) alloc((size_t)BG*NSEG*256*4);

  hipMemsetAsync(cnt,   0, (size_t)NTOT*4, stream);
  hipMemsetAsync(hgsum, 0, (size_t)BG*HD*4, stream);
  hipMemsetAsync(segU,  0, (size_t)BG*8*4, stream);

  k_count<<<256, 1024, 0, stream>>>(ei, cnt, acc);
  k_scan <<<BG, 1024, 0, stream>>>(cnt, x, eoP, cursor, csrc, xd);
  k_place<<<257, 1024, 0, stream>>>(ei, xd, cursor, csrc, acc,
                                    enc_w1, enc_b1, enc_w2, t1, AC1, nf1);

  k_pack<<<NTOT/256, 256, 0, stream>>>(xd, acc, eoP, cnt, t1, recN, srowA);

  k_enc_agg<<<1024, 256, 0, stream>>>(recN, csrc, (const float4*)AC1, enc_b2, nf1, hgsum);

  k_small<<<BG, 128, 0, stream>>>(hgsum, mu_w, mu_b, lv_w, lv_b, eps,
                                  zn_w, zn_b, dec_w1, dec_b1,
                                  out_mu, out_lv, out_z, t2, ushG, nf2);

  k_seg2<<<NTOT/256, 256, 0, stream>>>(t2, srowA, (float*)recN, segU);

  k_tab2rows<<<BG, 128, 0, stream>>>(ushG, dec_b1, dec_w2, segU, nf2, AC2);

  k_dec_agg<<<1024, 256, 0, stream>>>(recN, csrc, (const float4*)AC2,
                                      dec_b2, out_w, out_b, nf2, out_recon);
}

// Round 11
// 200.638 us; speedup vs baseline: 1.6929x; 1.6929x over previous
//
#include <hip/hip_runtime.h>
#include <math.h>

#define NTOT 262144   // total nodes
#define BG   64       // graphs
#define NNPG 4096     // nodes per graph
#define ET   1048576  // directed edges
#define EPG  16384    // edges per graph
#define EPB  4096     // edges per sub-block (4 sub-blocks/graph)
#define HD   128
#define LD   64
#define NSEG 129
#define SLOTPG 28672  // max padded slots per graph (EPG + 3*NNPG)
#define SLOTCAP (BG*SLOTPG)
#define TN   256      // nodes per agg tile (one per thread in phase 1)

// XCD-bijective swizzle for 256 blocks = 64 graphs x 4 sub-blocks:
// all 4 sub-blocks of graph g share (b&7) -> same XCD L2 for that graph's data
__device__ __forceinline__ void swz(int b, int& g, int& j){
  int xcd = b & 7, q = b >> 3;
  g = (q >> 2)*8 + xcd;
  j = q & 3;
}

// ---- count: LDS histogram per sub-block, planar merge (NO global atomics) ----
__global__ void __launch_bounds__(1024) k_count(const int* __restrict__ ei,
                                                int* __restrict__ cntJ){
  __shared__ int h[NNPG];
  int g, j; swz(blockIdx.x, g, j);
  int tid = threadIdx.x;
  #pragma unroll
  for (int k = tid; k < NNPG; k += 1024) h[k] = 0;
  __syncthreads();
  int gbase = g*NNPG;
  const int4* dsts4 = (const int4*)(ei + ET + g*EPG + j*EPB);
  int4 D = dsts4[tid];
  atomicAdd(&h[D.x - gbase], 1); atomicAdd(&h[D.y - gbase], 1);
  atomicAdd(&h[D.z - gbase], 1); atomicAdd(&h[D.w - gbase], 1);
  __syncthreads();
  int* plane = cntJ + j*NTOT + gbase;
  #pragma unroll
  for (int k = tid; k < NNPG; k += 1024) plane[k] = h[k];
}

// ---- scan: per-graph padded prefix sum + per-sub-block cursor bases ----
__global__ void __launch_bounds__(1024) k_scan(const int* __restrict__ cntJ,
                                               const float* __restrict__ x,
                                               int* __restrict__ cnt, int* __restrict__ off,
                                               int* __restrict__ cursJ,
                                               int* __restrict__ csrc, float2* __restrict__ xd){
  __shared__ int tsums[16];
  int g = blockIdx.x, tid = threadIdx.x, gbase = g*NNPG;
  int i0 = gbase + 4*tid;
  int4 c0 = *(const int4*)(cntJ + 0*NTOT + i0);
  int4 c1 = *(const int4*)(cntJ + 1*NTOT + i0);
  int4 c2 = *(const int4*)(cntJ + 2*NTOT + i0);
  int4 c3 = *(const int4*)(cntJ + 3*NTOT + i0);
  int n0 = c0.x+c1.x+c2.x+c3.x;
  int n1 = c0.y+c1.y+c2.y+c3.y;
  int n2 = c0.z+c1.z+c2.z+c3.z;
  int n3 = c0.w+c1.w+c2.w+c3.w;
  float4 xv = *(const float4*)(x + i0);
  int p0 = (n0+3)&~3, p1 = (n1+3)&~3, p2 = (n2+3)&~3, p3 = (n3+3)&~3;
  int tsum = p0+p1+p2+p3;
  int lane = tid & 63, wv = tid >> 6;
  int incl = tsum;
  #pragma unroll
  for (int dd = 1; dd < 64; dd <<= 1){
    int v = __shfl_up(incl, dd, 64);
    if (lane >= dd) incl += v;
  }
  if (lane == 63) tsums[wv] = incl;
  __syncthreads();
  if (tid < 64){
    int v = (tid < 16) ? tsums[tid] : 0;
    int inc2 = v;
    #pragma unroll
    for (int dd = 1; dd < 16; dd <<= 1){
      int t2 = __shfl_up(inc2, dd, 64);
      if (tid >= dd) inc2 += t2;
    }
    if (tid < 16) tsums[tid] = inc2 - v;
  }
  __syncthreads();
  int tbase = tsums[wv] + incl - tsum;
  int o0 = g*SLOTPG + tbase, o1 = o0+p0, o2 = o1+p1, o3 = o2+p2;
  *(int4*)(cnt + i0) = make_int4(n0, n1, n2, n3);
  *(int4*)(off + i0) = make_int4(o0, o1, o2, o3);
  // per-sub-block exclusive cursor bases: base_j = off + sum_{j'<j} cntJ[j']
  int b01 = o0 + c0.x, b02 = b01 + c1.x, b03 = b02 + c2.x;
  int b11 = o1 + c0.y, b12 = b11 + c1.y, b13 = b12 + c2.y;
  int b21 = o2 + c0.z, b22 = b21 + c1.z, b23 = b22 + c2.z;
  int b31 = o3 + c0.w, b32 = b31 + c1.w, b33 = b32 + c2.w;
  *(int4*)(cursJ + 0*NTOT + i0) = make_int4(o0,  o1,  o2,  o3);
  *(int4*)(cursJ + 1*NTOT + i0) = make_int4(b01, b11, b21, b31);
  *(int4*)(cursJ + 2*NTOT + i0) = make_int4(b02, b12, b22, b32);
  *(int4*)(cursJ + 3*NTOT + i0) = make_int4(b03, b13, b23, b33);
  float d0 = rsqrtf((float)n0 + 1.0f), d1 = rsqrtf((float)n1 + 1.0f);
  float d2 = rsqrtf((float)n2 + 1.0f), d3 = rsqrtf((float)n3 + 1.0f);
  float4* xd4 = (float4*)xd;
  xd4[i0/2 + 0] = make_float4(xv.x, d0, xv.y, d1);
  xd4[i0/2 + 1] = make_float4(xv.z, d2, xv.w, d3);
  for (int s = n0; s < p0; s++) csrc[o0+s] = -1;
  for (int s = n1; s < p1; s++) csrc[o1+s] = -1;
  for (int s = n2; s < p2; s++) csrc[o2+s] = -1;
  for (int s = n3; s < p3; s++) csrc[o3+s] = -1;
}

// ---- place (LDS cursors, exclusive slot sub-runs, NO global atomics) +
//      ax/s1 LDS accumulate -> planar accJ; block 256 runs tab1 ----
// tab1: relu(a*w1[j]+b1[j]) piecewise-linear; incremental over rank-sorted flips.
// AC float layout: s*256 + (k>>2)*8 + (k&3), +4 for C
__global__ void __launch_bounds__(1024) k_place(
    const int* __restrict__ ei, const float2* __restrict__ xd,
    const int* __restrict__ cursJ, int* __restrict__ csrc,
    float2* __restrict__ accJ,
    const float* __restrict__ w1, const float* __restrict__ b1,
    const float* __restrict__ w2,
    float* __restrict__ t1, float* __restrict__ AC1, int* __restrict__ nfp)
{
  __shared__ union {
    struct { int cur[NNPG]; float ax[NNPG]; float s1[NNPG]; } c;
    struct { float w2s[HD*HD]; float ts[128], ws[128], bs[128];
             int ks[128], jr[128]; } t;
  } u;
  int tid = threadIdx.x;
  if (blockIdx.x == 256){
    {
      const float4* src = (const float4*)w2;
      float4* dst = (float4*)u.t.w2s;
      for (int idx = tid; idx < HD*HD/4; idx += 1024) dst[idx] = src[idx];
    }
    if (tid < 128){
      float w = w1[tid], b = b1[tid];
      float t; int kind;
      if (w != 0.0f){ t = -b / w; kind = (w > 0.0f) ? 0 : 1; }
      else          { t = INFINITY; kind = 2; }
      u.t.ts[tid] = t; u.t.ks[tid] = kind; u.t.ws[tid] = w; u.t.bs[tid] = b;
      u.t.jr[tid] = -1;
    }
    __syncthreads();
    if (tid == 0){
      int c = 0;
      for (int q = 0; q < 128; q++) c += (u.t.ks[q] != 2) ? 1 : 0;
      nfp[0] = c;
    }
    if (tid < 128){
      int j = tid;
      float t = u.t.ts[j];
      int r = 0;
      for (int q = 0; q < 128; q++){
        if (u.t.ks[q] != 2){
          float tq = u.t.ts[q];
          if (tq < t || (tq == t && q < j)) r++;
        }
      }
      t1[j] = t;
      if (u.t.ks[j] != 2) u.t.jr[r] = j;
    }
    __syncthreads();
    if (tid < 128){
      int k = tid;
      float a = 0.f, c = 0.f;
      for (int q = 0; q < 128; q++){    // segment 0: kind1 all active
        int kd = u.t.ks[q];
        bool act = (kd == 1) || (kd == 2 && u.t.bs[q] > 0.0f);
        if (act){ float v = u.t.w2s[q*HD + k]; a = fmaf(u.t.ws[q], v, a); c = fmaf(u.t.bs[q], v, c); }
      }
      int base = (k>>2)*8 + (k&3);
      AC1[base] = a; AC1[base+4] = c;
      for (int s = 0; s < 128; s++){
        int q = u.t.jr[s];
        if (q >= 0){
          float sg = (u.t.ks[q] == 0) ? 1.f : -1.f;
          float v  = u.t.w2s[q*HD + k];
          a = fmaf(sg*u.t.ws[q], v, a);
          c = fmaf(sg*u.t.bs[q], v, c);
        }
        int o = (s+1)*256 + base;
        AC1[o] = a; AC1[o+4] = c;
      }
    }
    return;
  }
  int g, j; swz(blockIdx.x, g, j);
  int gbase = g*NNPG;
  const int4* srcs4 = (const int4*)(ei + g*EPG + j*EPB);
  const int4* dsts4 = (const int4*)(ei + ET + g*EPG + j*EPB);
  int4 S = srcs4[tid], D = dsts4[tid];
  {
    const int4* cp = (const int4*)(cursJ + j*NTOT + gbase);
    *(int4*)(u.c.cur + 4*tid) = cp[tid];
    *(float4*)(u.c.ax + 4*tid) = make_float4(0.f,0.f,0.f,0.f);
    *(float4*)(u.c.s1 + 4*tid) = make_float4(0.f,0.f,0.f,0.f);
  }
  __syncthreads();
  #define PL(s_, d_) { int dl = (d_) - gbase; float2 sd = xd[s_]; \
    int p_ = atomicAdd(&u.c.cur[dl], 1); \
    csrc[p_] = (s_); \
    atomicAdd(&u.c.ax[dl], sd.y * sd.x); \
    atomicAdd(&u.c.s1[dl], sd.y); }
  PL(S.x, D.x); PL(S.y, D.y); PL(S.z, D.z); PL(S.w, D.w);
  #undef PL
  __syncthreads();
  float4* ap4 = (float4*)(accJ + (size_t)j*NTOT + gbase);
  ap4[2*tid+0] = make_float4(u.c.ax[4*tid+0], u.c.s1[4*tid+0],
                             u.c.ax[4*tid+1], u.c.s1[4*tid+1]);
  ap4[2*tid+1] = make_float4(u.c.ax[4*tid+2], u.c.s1[4*tid+2],
                             u.c.ax[4*tid+3], u.c.s1[4*tid+3]);
}

// ---- pack per-node records: recN[2i]=(d, d*ax, d*srow, segE),
// recN[2i+1]=(eo,np,0,0); srowA for decoder segs
__global__ void k_pack(const float2* __restrict__ xd, const float2* __restrict__ accJ,
                       const int* __restrict__ off, const int* __restrict__ cnt,
                       const float* __restrict__ t1,
                       float4* __restrict__ recN, float* __restrict__ srowA){
  __shared__ float ts[128];
  if (threadIdx.x < 128) ts[threadIdx.x] = t1[threadIdx.x];
  __syncthreads();
  int i = blockIdx.x*256 + threadIdx.x;
  int n = cnt[i], eo = off[i];
  float di = rsqrtf((float)n + 1.0f);
  float2 xdv = xd[i];
  float2 a0 = accJ[0*NTOT + i], a1 = accJ[1*NTOT + i];
  float2 a2 = accJ[2*NTOT + i], a3 = accJ[3*NTOT + i];
  float axs = (a0.x + a1.x) + (a2.x + a3.x);
  float s1s = (a0.y + a1.y) + (a2.y + a3.y);
  float ax = di * (di * xdv.x + axs);
  float sr = di * (di + s1s);
  int sc = 0;
  for (int q = 0; q < 128; q++) sc += (ts[q] < ax) ? 1 : 0;
  int np = (n + 3) & ~3;
  recN[2*i]   = make_float4(di, di*ax, di*sr, __int_as_float(sc));
  recN[2*i+1] = make_float4(__int_as_float(eo), __int_as_float(np), 0.f, 0.f);
  srowA[i] = sr;
}

// ---------------- fused encoder GCN2 + relu + mean-pool ----------------
__global__ void __launch_bounds__(256) k_enc_agg(
    const float4* __restrict__ recN, const int* __restrict__ csrc,
    const float4* __restrict__ AC, const float* __restrict__ b2,
    const int* __restrict__ nfp, float* __restrict__ hgsum)
{
  __shared__ float4 sS[TN];
  __shared__ float4 sRA[TN];
  __shared__ int sFlag[TN];
  __shared__ float red[256*4];
  int bid = blockIdx.x, g = bid & 63, part = bid >> 6;   // 1024 blocks
  int tid = threadIdx.x, lane = tid & 31, nrow = tid >> 5;
  int base = g*NNPG + part*TN;
  int nf = nfp[0];
  {
    int i = base + tid;
    sRA[tid] = recN[2*i];
    float4 rB = recN[2*i+1];
    int eo = __float_as_int(rB.x), np = __float_as_int(rB.y);
    float swa=0.f, sw=0.f, swaN=0.f, swN=0.f;
    int flag = 0;
    for (int t = 0; t < np; t += 4){
      int4 ss = *(const int4*)(csrc + eo + t);
      #pragma unroll
      for (int uu = 0; uu < 4; uu++){
        int s = (uu==0)?ss.x:(uu==1)?ss.y:(uu==2)?ss.z:ss.w;
        if (s >= 0){
          float4 r = recN[2*s];
          int sb = __float_as_int(r.w);
          swa += r.y; sw += r.x;
          bool isN = (sb == nf) && (sb != 0);
          swaN += isN ? r.y : 0.f;
          swN  += isN ? r.x : 0.f;
          flag |= (sb != 0 && sb != nf) ? 1 : 0;
        }
      }
    }
    sS[tid] = make_float4(swa, sw, swaN, swN);
    sFlag[tid] = flag;
  }
  __syncthreads();
  const float4* q0 = AC + (size_t)lane*2;
  const float4* qn = AC + ((size_t)nf*32 + lane)*2;
  float4 A0 = q0[0], C0 = q0[1], An = qn[0], Cn = qn[1];
  float4 dA = make_float4(An.x-A0.x, An.y-A0.y, An.z-A0.z, An.w-A0.w);
  float4 dC = make_float4(Cn.x-C0.x, Cn.y-C0.y, Cn.z-C0.z, Cn.w-C0.w);
  float4 bb = ((const float4*)b2)[lane];
  float gx=0.f, gy=0.f, gz=0.f, gw=0.f;
  for (int it = 0; it < TN/8; ++it){
    int li = it*8 + nrow;
    int i = base + li;
    float4 rA = sRA[li];
    float accx, accy, accz, accw;
    if (sFlag[li]){              // rare slow path: full 32-wide recompute
      float4 rB = recN[2*i+1];
      int eo = __float_as_int(rB.x), np = __float_as_int(rB.y);
      float swa=0.f, sw=0.f, swaN=0.f, swN=0.f;
      float mx=0.f, my=0.f, mz=0.f, mw=0.f;
      for (int t = 0; t < np; ++t){
        int s = csrc[eo+t];
        if (s < 0) continue;
        float4 r = recN[2*s];
        int sb = __float_as_int(r.w);
        float v = r.y;
        swa += v; sw += r.x;
        bool isN = (sb == nf) && (sb != 0);
        swaN += isN ? v : 0.f; swN += isN ? r.x : 0.f;
        if (sb != 0 && sb != nf){
          const float4* qm = AC + ((size_t)sb*32 + lane)*2;
          float4 qa = qm[0], qc = qm[1];
          mx = fmaf(v, qa.x-A0.x, fmaf(r.x, qc.x-C0.x, mx));
          my = fmaf(v, qa.y-A0.y, fmaf(r.x, qc.y-C0.y, my));
          mz = fmaf(v, qa.z-A0.z, fmaf(r.x, qc.z-C0.z, mz));
          mw = fmaf(v, qa.w-A0.w, fmaf(r.x, qc.w-C0.w, mw));
        }
      }
      accx = fmaf(swa,A0.x, fmaf(swaN,dA.x, fmaf(sw,C0.x, fmaf(swN,dC.x, mx))));
      accy = fmaf(swa,A0.y, fmaf(swaN,dA.y, fmaf(sw,C0.y, fmaf(swN,dC.y, my))));
      accz = fmaf(swa,A0.z, fmaf(swaN,dA.z, fmaf(sw,C0.z, fmaf(swN,dC.z, mz))));
      accw = fmaf(swa,A0.w, fmaf(swaN,dA.w, fmaf(sw,C0.w, fmaf(swN,dC.w, mw))));
    } else {
      float4 s4 = sS[li];
      accx = fmaf(s4.x,A0.x, fmaf(s4.z,dA.x, fmaf(s4.y,C0.x, s4.w*dC.x)));
      accy = fmaf(s4.x,A0.y, fmaf(s4.z,dA.y, fmaf(s4.y,C0.y, s4.w*dC.y)));
      accz = fmaf(s4.x,A0.z, fmaf(s4.z,dA.z, fmaf(s4.y,C0.z, s4.w*dC.z)));
      accw = fmaf(s4.x,A0.w, fmaf(s4.z,dA.w, fmaf(s4.y,C0.w, s4.w*dC.w)));
    }
    int si = __float_as_int(rA.w);
    bool m0 = (si == 0);
    float4 sa, sc;
    sa.x = m0 ? A0.x : An.x; sa.y = m0 ? A0.y : An.y; sa.z = m0 ? A0.z : An.z; sa.w = m0 ? A0.w : An.w;
    sc.x = m0 ? C0.x : Cn.x; sc.y = m0 ? C0.y : Cn.y; sc.z = m0 ? C0.z : Cn.z; sc.w = m0 ? C0.w : Cn.w;
    if (si != 0 && si != nf){
      const float4* qs = AC + ((size_t)si*32 + lane)*2;
      sa = qs[0]; sc = qs[1];
    }
    float d = rA.x, d2 = d*d, ca = rA.y*d;
    gx += fmaxf(fmaf(d, accx, fmaf(ca, sa.x, d2*sc.x)) + bb.x, 0.f);
    gy += fmaxf(fmaf(d, accy, fmaf(ca, sa.y, d2*sc.y)) + bb.y, 0.f);
    gz += fmaxf(fmaf(d, accz, fmaf(ca, sa.z, d2*sc.z)) + bb.z, 0.f);
    gw += fmaxf(fmaf(d, accw, fmaf(ca, sa.w, d2*sc.w)) + bb.w, 0.f);
  }
  __syncthreads();
  red[tid*4+0] = gx; red[tid*4+1] = gy; red[tid*4+2] = gz; red[tid*4+3] = gw;
  __syncthreads();
  if (nrow == 0){
    float tx=0.f, ty=0.f, tz=0.f, tw=0.f;
    for (int r2 = 0; r2 < 8; r2++){
      int t2 = (r2*32 + lane)*4;
      tx += red[t2]; ty += red[t2+1]; tz += red[t2+2]; tw += red[t2+3];
    }
    atomicAdd(&hgsum[g*HD + lane*4 + 0], tx);
    atomicAdd(&hgsum[g*HD + lane*4 + 1], ty);
    atomicAdd(&hgsum[g*HD + lane*4 + 2], tz);
    atomicAdd(&hgsum[g*HD + lane*4 + 3], tw);
  }
}

// ------- per-graph dense chain (slim: no table build) -------
__global__ void __launch_bounds__(128) k_small(
    const float* __restrict__ hgsum,
    const float* __restrict__ mu_w, const float* __restrict__ mu_b,
    const float* __restrict__ lv_w, const float* __restrict__ lv_b,
    const float* __restrict__ eps,
    const float* __restrict__ zn_w, const float* __restrict__ zn_b,
    const float* __restrict__ dec_w1, const float* __restrict__ dec_b1,
    float* __restrict__ out_mu, float* __restrict__ out_lv, float* __restrict__ out_z,
    float* __restrict__ t2, float* __restrict__ ushG, int* __restrict__ nf2)
{
  int g = blockIdx.x, tid = threadIdx.x;
  __shared__ float hg[128], zsh[64], znsh[128];
  __shared__ int ks[128];
  hg[tid] = hgsum[g*HD + tid] * (1.0f/4096.0f);
  __syncthreads();
  if (tid < 64){
    int l = tid;
    float m = mu_b[l], v = lv_b[l];
    for (int k = 0; k < HD; k++){
      float hv = hg[k];
      m = fmaf(hv, mu_w[k*LD + l], m);
      v = fmaf(hv, lv_w[k*LD + l], v);
    }
    int o = g*LD + l;
    out_mu[o] = m; out_lv[o] = v;
    float zv = fmaf(expf(0.5f*v), eps[o], m);
    out_z[o] = zv; zsh[l] = zv;
  }
  __syncthreads();
  {
    int k = tid;
    float acc = zn_b[k];
    for (int l = 0; l < LD; l++) acc = fmaf(zsh[l], zn_w[l*HD + k], acc);
    znsh[k] = acc;
  }
  __syncthreads();
  float w;
  {
    int k = tid;
    float acc = 0.f;
    for (int j = 0; j < HD; j++) acc = fmaf(znsh[j], dec_w1[j*HD + k], acc);
    ushG[g*HD + k] = acc;
    w = acc;
  }
  float b = dec_b1[tid];
  float t; int kind;
  if (w != 0.0f){ t = -b / w; kind = (w > 0.0f) ? 0 : 1; }
  else          { t = INFINITY; kind = 2; }
  t2[g*HD + tid] = t; ks[tid] = kind;
  __syncthreads();
  if (tid == 0){
    int c = 0;
    for (int q = 0; q < 128; q++) c += (ks[q] != 2) ? 1 : 0;
    nf2[g] = c;
  }
}

// segD per node -> overwrite recN[2i].y (d*ax, dead after encoder) + used bitmap
__global__ void k_seg2(const float* __restrict__ t2, const float* __restrict__ srowA,
                       float* __restrict__ recNf, int* __restrict__ segUsed){
  __shared__ float ts[128];
  __shared__ int used[8];
  int tid = threadIdx.x;
  int i = blockIdx.x*256 + tid;
  int g = blockIdx.x >> 4;
  if (tid < 128) ts[tid] = t2[g*HD + tid];
  if (tid < 8) used[tid] = 0;
  __syncthreads();
  float a = srowA[i];
  int sc = 0;
  for (int q = 0; q < 128; q++) sc += (ts[q] < a) ? 1 : 0;
  recNf[(2*i)*4 + 1] = __int_as_float(sc);
  atomicOr(&used[sc>>5], 1u << (sc & 31));
  __syncthreads();
  if (tid < 8 && used[tid]) atomicOr(&segUsed[g*8 + tid], used[tid]);
}

// ---- build only the USED decoder table rows (plus rows 0 and nf) ----
__global__ void __launch_bounds__(128) k_tab2rows(
    const float* __restrict__ ushG, const float* __restrict__ dec_b1,
    const float* __restrict__ w2, const int* __restrict__ segUsed,
    const int* __restrict__ nf2, float* __restrict__ AC2)
{
  __shared__ float w2s[HD*HD];
  __shared__ float ws[128], bs[128], tsh[128];
  __shared__ int ks[128], rr[128];
  int g = blockIdx.x, j = threadIdx.x;
  {
    const float4* src = (const float4*)w2;
    float4* dst = (float4*)w2s;
    #pragma unroll
    for (int idx = 0; idx < HD*HD/4/128; idx++) dst[idx*128 + j] = src[idx*128 + j];
  }
  float w = ushG[g*HD + j], b = dec_b1[j];
  float t; int kind;
  if (w != 0.0f){ t = -b / w; kind = (w > 0.0f) ? 0 : 1; }
  else          { t = INFINITY; kind = 2; }
  ws[j] = w; bs[j] = b; tsh[j] = t; ks[j] = kind;
  __syncthreads();
  int r = 0;
  for (int q = 0; q < 128; q++){
    if (ks[q] != 2){
      float tq = tsh[q];
      if (tq < t || (tq == t && q < j)) r++;
    }
  }
  rr[j] = r;
  __syncthreads();
  int nf = nf2[g];
  float* ACg = AC2 + (size_t)g*NSEG*256;
  int base = (j>>2)*8 + (j&3);
  for (int wd = 0; wd < 5; wd++){
    unsigned m = (unsigned)segUsed[g*8 + wd];
    if (wd == 0) m |= 1u;
    if ((nf >> 5) == wd) m |= 1u << (nf & 31);
    while (m){
      int bit = __ffs(m) - 1;
      m &= m - 1;
      int s = wd*32 + bit;
      float a = 0.f, c = 0.f;
      #pragma unroll 8
      for (int q = 0; q < 128; q++){
        int kd = ks[q];
        bool act = (kd == 0) ? (rr[q] < s) : (kd == 1) ? (rr[q] >= s) : (bs[q] > 0.0f);
        float v = act ? w2s[q*HD + j] : 0.0f;
        a = fmaf(ws[q], v, a); c = fmaf(bs[q], v, c);
      }
      ACg[s*256 + base] = a; ACg[s*256 + base + 4] = c;
    }
  }
}

// ---------------- fused decoder GCN2 + relu + out-proj + tanh ----------------
// recN[2i] = (d, segD, d*srow, segE_unused)
__global__ void __launch_bounds__(256) k_dec_agg(
    const float4* __restrict__ recN, const int* __restrict__ csrc,
    const float4* __restrict__ AC2, const float* __restrict__ b2,
    const float* __restrict__ ow, const float* __restrict__ ob,
    const int* __restrict__ nf2, float* __restrict__ recon)
{
  __shared__ float4 sS[TN];
  __shared__ float4 sRA[TN];
  __shared__ int sFlag[TN];
  int bid = blockIdx.x, g = bid & 63, part = bid >> 6;
  int tid = threadIdx.x, lane = tid & 31, nrow = tid >> 5;
  int base = g*NNPG + part*TN;
  int nf = nf2[g];
  const float4* AC = AC2 + (size_t)g*NSEG*64;
  {
    int i = base + tid;
    sRA[tid] = recN[2*i];
    float4 rB = recN[2*i+1];
    int eo = __float_as_int(rB.x), np = __float_as_int(rB.y);
    float swa=0.f, sw=0.f, swaN=0.f, swN=0.f;
    int flag = 0;
    for (int t = 0; t < np; t += 4){
      int4 ss = *(const int4*)(csrc + eo + t);
      #pragma unroll
      for (int uu = 0; uu < 4; uu++){
        int s = (uu==0)?ss.x:(uu==1)?ss.y:(uu==2)?ss.z:ss.w;
        if (s >= 0){
          float4 r = recN[2*s];
          int sb = __float_as_int(r.y);
          swa += r.z; sw += r.x;
          bool isN = (sb == nf) && (sb != 0);
          swaN += isN ? r.z : 0.f;
          swN  += isN ? r.x : 0.f;
          flag |= (sb != 0 && sb != nf) ? 1 : 0;
        }
      }
    }
    sS[tid] = make_float4(swa, sw, swaN, swN);
    sFlag[tid] = flag;
  }
  __syncthreads();
  const float4* q0 = AC + (size_t)lane*2;
  const float4* qn = AC + ((size_t)nf*32 + lane)*2;
  float4 A0 = q0[0], C0 = q0[1], An = qn[0], Cn = qn[1];
  float4 dA = make_float4(An.x-A0.x, An.y-A0.y, An.z-A0.z, An.w-A0.w);
  float4 dC = make_float4(Cn.x-C0.x, Cn.y-C0.y, Cn.z-C0.z, Cn.w-C0.w);
  float4 bb  = ((const float4*)b2)[lane];
  float4 owv = ((const float4*)ow)[lane];
  float obv = ob[0];
  for (int it = 0; it < TN/8; ++it){
    int li = it*8 + nrow;
    int i = base + li;
    float4 rA = sRA[li];
    float accx, accy, accz, accw;
    if (sFlag[li]){              // rare slow path
      float4 rB = recN[2*i+1];
      int eo = __float_as_int(rB.x), np = __float_as_int(rB.y);
      float swa=0.f, sw=0.f, swaN=0.f, swN=0.f;
      float mx=0.f, my=0.f, mz=0.f, mw=0.f;
      for (int t = 0; t < np; ++t){
        int s = csrc[eo+t];
        if (s < 0) continue;
        float4 r = recN[2*s];
        int sb = __float_as_int(r.y);
        float v = r.z;
        swa += v; sw += r.x;
        bool isN = (sb == nf) && (sb != 0);
        swaN += isN ? v : 0.f; swN += isN ? r.x : 0.f;
        if (sb != 0 && sb != nf){
          const float4* qm = AC + ((size_t)sb*32 + lane)*2;
          float4 qa = qm[0], qc = qm[1];
          mx = fmaf(v, qa.x-A0.x, fmaf(r.x, qc.x-C0.x, mx));
          my = fmaf(v, qa.y-A0.y, fmaf(r.x, qc.y-C0.y, my));
          mz = fmaf(v, qa.z-A0.z, fmaf(r.x, qc.z-C0.z, mz));
          mw = fmaf(v, qa.w-A0.w, fmaf(r.x, qc.w-C0.w, mw));
        }
      }
      accx = fmaf(swa,A0.x, fmaf(swaN,dA.x, fmaf(sw,C0.x, fmaf(swN,dC.x, mx))));
      accy = fmaf(swa,A0.y, fmaf(swaN,dA.y, fmaf(sw,C0.y, fmaf(swN,dC.y, my))));
      accz = fmaf(swa,A0.z, fmaf(swaN,dA.z, fmaf(sw,C0.z, fmaf(swN,dC.z, mz))));
      accw = fmaf(swa,A0.w, fmaf(swaN,dA.w, fmaf(sw,C0.w, fmaf(swN,dC.w, mw))));
    } else {
      float4 s4 = sS[li];
      accx = fmaf(s4.x,A0.x, fmaf(s4.z,dA.x, fmaf(s4.y,C0.x, s4.w*dC.x)));
      accy = fmaf(s4.x,A0.y, fmaf(s4.z,dA.y, fmaf(s4.y,C0.y, s4.w*dC.y)));
      accz = fmaf(s4.x,A0.z, fmaf(s4.z,dA.z, fmaf(s4.y,C0.z, s4.w*dC.z)));
      accw = fmaf(s4.x,A0.w, fmaf(s4.z,dA.w, fmaf(s4.y,C0.w, s4.w*dC.w)));
    }
    int si = __float_as_int(rA.y);
    bool m0 = (si == 0);
    float4 sa, sc;
    sa.x = m0 ? A0.x : An.x; sa.y = m0 ? A0.y : An.y; sa.z = m0 ? A0.z : An.z; sa.w = m0 ? A0.w : An.w;
    sc.x = m0 ? C0.x : Cn.x; sc.y = m0 ? C0.y : Cn.y; sc.z = m0 ? C0.z : Cn.z; sc.w = m0 ? C0.w : Cn.w;
    if (si != 0 && si != nf){
      const float4* qs = AC + ((size_t)si*32 + lane)*2;
      sa = qs[0]; sc = qs[1];
    }
    float d = rA.x, d2 = d*d, ca = rA.z*d;
    float hx = fmaxf(fmaf(d, accx, fmaf(ca, sa.x, d2*sc.x)) + bb.x, 0.f);
    float hy = fmaxf(fmaf(d, accy, fmaf(ca, sa.y, d2*sc.y)) + bb.y, 0.f);
    float hz = fmaxf(fmaf(d, accz, fmaf(ca, sa.z, d2*sc.z)) + bb.z, 0.f);
    float hw = fmaxf(fmaf(d, accw, fmaf(ca, sa.w, d2*sc.w)) + bb.w, 0.f);
    float dsum = hx*owv.x + hy*owv.y + hz*owv.z + hw*owv.w;
    for (int o2 = 16; o2 > 0; o2 >>= 1) dsum += __shfl_down(dsum, o2, 32);
    if (lane == 0) recon[i] = tanhf(dsum + obv);
  }
}

// ---------------- launch ----------------
extern "C" void kernel_launch(void* const* d_in, const int* in_sizes, int n_in,
                              void* d_out, int out_size, void* d_ws, size_t ws_size,
                              hipStream_t stream){
  (void)in_sizes; (void)n_in; (void)out_size; (void)ws_size;
  const float* x      = (const float*)d_in[0];
  const float* eps    = (const float*)d_in[1];
  const float* enc_w1 = (const float*)d_in[2];
  const float* enc_b1 = (const float*)d_in[3];
  const float* enc_w2 = (const float*)d_in[4];
  const float* enc_b2 = (const float*)d_in[5];
  const float* mu_w   = (const float*)d_in[6];
  const float* mu_b   = (const float*)d_in[7];
  const float* lv_w   = (const float*)d_in[8];
  const float* lv_b   = (const float*)d_in[9];
  const float* zn_w   = (const float*)d_in[10];
  const float* zn_b   = (const float*)d_in[11];
  const float* dec_w1 = (const float*)d_in[12];
  const float* dec_b1 = (const float*)d_in[13];
  const float* dec_w2 = (const float*)d_in[14];
  const float* dec_b2 = (const float*)d_in[15];
  const float* out_w  = (const float*)d_in[16];
  const float* out_b  = (const float*)d_in[17];
  const int*   ei     = (const int*)d_in[18];

  float* out       = (float*)d_out;
  float* out_recon = out;
  float* out_mu    = out + NTOT;
  float* out_lv    = out_mu + BG*LD;
  float* out_z     = out_lv + BG*LD;

  char* w = (char*)d_ws;
  size_t off_b = 0;
  auto alloc = [&](size_t bytes)->void*{
    void* p = w + off_b;
    off_b += (bytes + 255) & ~(size_t)255;
    return p;
  };
  int*    cnt    = (int*)   alloc((size_t)NTOT*4);
  int*    eoP    = (int*)   alloc((size_t)NTOT*4);
  int*    cntJ   = (int*)   alloc((size_t)4*NTOT*4);
  int*    cursJ  = (int*)   alloc((size_t)4*NTOT*4);
  int*    csrc   = (int*)   alloc((size_t)SLOTCAP*4);
  float2* xd     = (float2*)alloc((size_t)NTOT*8);
  float2* accJ   = (float2*)alloc((size_t)4*NTOT*8);
  float4* recN   = (float4*)alloc(((size_t)NTOT*2 + 32)*16);
  float*  srowA  = (float*) alloc((size_t)NTOT*4);
  float*  t1     = (float*) alloc(128*4);
  int*    nf1    = (int*)   alloc(256);
  int*    nf2    = (int*)   alloc(BG*4);
  int*    segU   = (int*)   alloc(BG*8*4);
  float*  ushG   = (float*) alloc((size_t)BG*HD*4);
  float*  AC1    = (float*) alloc((size_t)NSEG*256*4);
  float*  hgsum  = (float*) alloc((size_t)BG*HD*4);
  float*  t2     = (float*) alloc((size_t)BG*HD*4);
  float*  AC2    = (float*) alloc((size_t)BG*NSEG*256*4);

  hipMemsetAsync(hgsum, 0, (size_t)BG*HD*4, stream);
  hipMemsetAsync(segU,  0, (size_t)BG*8*4, stream);

  k_count<<<256, 1024, 0, stream>>>(ei, cntJ);
  k_scan <<<BG, 1024, 0, stream>>>(cntJ, x, cnt, eoP, cursJ, csrc, xd);
  k_place<<<257, 1024, 0, stream>>>(ei, xd, cursJ, csrc, accJ,
                                    enc_w1, enc_b1, enc_w2, t1, AC1, nf1);

  k_pack<<<NTOT/256, 256, 0, stream>>>(xd, accJ, eoP, cnt, t1, recN, srowA);

  k_enc_agg<<<1024, 256, 0, stream>>>(recN, csrc, (const float4*)AC1, enc_b2, nf1, hgsum);

  k_small<<<BG, 128, 0, stream>>>(hgsum, mu_w, mu_b, lv_w, lv_b, eps,
                                  zn_w, zn_b, dec_w1, dec_b1,
                                  out_mu, out_lv, out_z, t2, ushG, nf2);

  k_seg2<<<NTOT/256, 256, 0, stream>>>(t2, srowA, (float*)recN, segU);

  k_tab2rows<<<BG, 128, 0, stream>>>(ushG, dec_b1, dec_w2, segU, nf2, AC2);

  k_dec_agg<<<1024, 256, 0, stream>>>(recN, csrc, (const float4*)AC2,
                                      dec_b2, out_w, out_b, nf2, out_recon);
}